// Round 2
// baseline (103.061 us; speedup 1.0000x reference)
//
#include <hip/hip_runtime.h>

typedef __bf16 bf16x8 __attribute__((ext_vector_type(8)));
typedef float  f32x4  __attribute__((ext_vector_type(4)));

#define MFMA(A, B, C) __builtin_amdgcn_mfma_f32_16x16x32_bf16((A), (B), (C), 0, 0, 0)

// Fused MLP: x=[h(64),b_in,b_out,J,-J] -> 64 relu -> 64 relu -> 5
// Out^T = W^T X^T per 16-row tile, mfma_f32_16x16x32_bf16, rows at lane&15.
// Bijections (q=lane>>4, i=elem):
//   layer1 kk=0,1 : f = 16q + 8kk + i   -> lane reads h[row][16q..16q+15] = 64B contiguous
//   layer1 kk=2   : i=0 -> f=64+q (scalar feature per q-group; -J sign folded into weight)
//                   i=1 -> f=68 bias-as-feature (q==0 lanes carry constant 1)
//   layer2/3      : f = 16*(2kk+(i>>2)) + 4q + (i&3)  (matches prev layer's D layout -> lane-local repack)
// 2 tiles (32 rows) per iteration, pair-deep prefetch (~8.5 KB in flight/wave).
__global__ __launch_bounds__(256, 2)
void msg_mlp(const float* __restrict__ hbuf, const float* __restrict__ Jbuf,
             const float* __restrict__ binb, const float* __restrict__ boutb,
             const float* __restrict__ W1, const float* __restrict__ b1,
             const float* __restrict__ W2, const float* __restrict__ b2,
             const float* __restrict__ W3, const float* __restrict__ b3,
             float* __restrict__ out, int n_rows, int n_pairs)
{
    const int lane = threadIdx.x & 63;
    const int e = lane & 15;   // row-within-tile (B n-index and D col)
    const int q = lane >> 4;   // k-group
    const int wid = blockIdx.x * (blockDim.x >> 6) + (threadIdx.x >> 6);
    const int nw  = gridDim.x * (blockDim.x >> 6);

    // ---------------- weight fragments (register-resident, loaded once) ----------------
    bf16x8 a1[4][2];   // layer1 h-features, f = 16q + 8kk + i
#pragma unroll
    for (int mt = 0; mt < 4; ++mt)
#pragma unroll
      for (int kk = 0; kk < 2; ++kk)
#pragma unroll
        for (int i = 0; i < 8; ++i)
          a1[mt][kk][i] = (__bf16)W1[(16*q + 8*kk + i)*64 + 16*mt + e];

    bf16x8 a1x[4];     // layer1 scalar features + bias column
#pragma unroll
    for (int mt = 0; mt < 4; ++mt) {
      const int o = 16*mt + e;
      float w0;
      if      (q == 0) w0 =  W1[64*64 + o];   // b_in
      else if (q == 1) w0 =  W1[65*64 + o];   // b_out
      else if (q == 2) w0 =  W1[66*64 + o];   // J
      else             w0 = -W1[67*64 + o];   // -J: sign folded into weight, lane loads +J
      a1x[mt][0] = (__bf16)w0;
      a1x[mt][1] = (q == 0) ? (__bf16)b1[o] : (__bf16)0.0f;
#pragma unroll
      for (int i = 2; i < 8; ++i) a1x[mt][i] = (__bf16)0.0f;
    }

    bf16x8 a2[4][2];   // layer2: K=64
#pragma unroll
    for (int mt = 0; mt < 4; ++mt)
#pragma unroll
      for (int kk = 0; kk < 2; ++kk)
#pragma unroll
        for (int i = 0; i < 8; ++i) {
          const int f = 16*(2*kk + (i>>2)) + 4*q + (i&3);
          a2[mt][kk][i] = (__bf16)W2[f*64 + 16*mt + e];
        }
    bf16x8 a3[2];      // layer3: 5 outs (rest zero)
#pragma unroll
    for (int kk = 0; kk < 2; ++kk)
#pragma unroll
      for (int i = 0; i < 8; ++i) {
        const int f = 16*(2*kk + (i>>2)) + 4*q + (i&3);
        a3[kk][i] = (e < 5) ? (__bf16)W3[f*5 + e] : (__bf16)0.0f;
      }
    float b2r[4][4];   // D layout: out = 16mt + 4q + r
#pragma unroll
    for (int mt = 0; mt < 4; ++mt)
#pragma unroll
      for (int r = 0; r < 4; ++r) b2r[mt][r] = b2[16*mt + 4*q + r];
    float b3r[4];
#pragma unroll
    for (int r = 0; r < 4; ++r) b3r[r] = (4*q + r < 5) ? b3[4*q + r] : 0.0f;

    // per-lane uniform scalar stream (no divergence; q==3 reads +J, sign is in weight)
    const float* sptr = (q == 0) ? binb : (q == 1) ? boutb : Jbuf;
    const __bf16 biasf = (q == 0) ? (__bf16)1.0f : (__bf16)0.0f;

    // ---------------- per-tile input load: 64B contiguous per lane + 1 scalar ----------------
    auto issue = [&](int tt, f32x4& h0, f32x4& h1, f32x4& h2, f32x4& h3, float& s) {
      int re = tt * 16 + e;
      if (re >= n_rows) re = n_rows - 1;        // clamp (garbage compute, store guarded)
      const float* hr = hbuf + (size_t)re * 64 + q * 16;
      h0 = *(const f32x4*)(hr);
      h1 = *(const f32x4*)(hr + 4);
      h2 = *(const f32x4*)(hr + 8);
      h3 = *(const f32x4*)(hr + 12);
      s = sptr[re];
    };

    auto compute_store = [&](f32x4 h0, f32x4 h1, f32x4 h2, f32x4 h3, float s, int tt) {
      bf16x8 xb0, xb1, xb2;
#pragma unroll
      for (int i = 0; i < 4; ++i) {
        xb0[i]     = (__bf16)h0[i];
        xb0[i + 4] = (__bf16)h1[i];
        xb1[i]     = (__bf16)h2[i];
        xb1[i + 4] = (__bf16)h3[i];
      }
      xb2[0] = (__bf16)s; xb2[1] = biasf;
#pragma unroll
      for (int i = 2; i < 8; ++i) xb2[i] = (__bf16)0.0f;

      // ---- layer 1: [68->64] + relu ----
      f32x4 acc1[4];
#pragma unroll
      for (int mt = 0; mt < 4; ++mt) {
        acc1[mt] = (f32x4){0.f, 0.f, 0.f, 0.f};
        acc1[mt] = MFMA(a1[mt][0], xb0, acc1[mt]);
        acc1[mt] = MFMA(a1[mt][1], xb1, acc1[mt]);
        acc1[mt] = MFMA(a1x[mt],   xb2, acc1[mt]);
      }
      bf16x8 y[2];   // lane-local repack
#pragma unroll
      for (int kk = 0; kk < 2; ++kk)
#pragma unroll
        for (int i = 0; i < 8; ++i)
          y[kk][i] = (__bf16)fmaxf(acc1[2*kk + (i>>2)][i & 3], 0.0f);

      // ---- layer 2: [64->64] + relu ----
      f32x4 acc2[4];
#pragma unroll
      for (int mt = 0; mt < 4; ++mt) {
        acc2[mt] = (f32x4){b2r[mt][0], b2r[mt][1], b2r[mt][2], b2r[mt][3]};
        acc2[mt] = MFMA(a2[mt][0], y[0], acc2[mt]);
        acc2[mt] = MFMA(a2[mt][1], y[1], acc2[mt]);
      }
      bf16x8 z[2];
#pragma unroll
      for (int kk = 0; kk < 2; ++kk)
#pragma unroll
        for (int i = 0; i < 8; ++i)
          z[kk][i] = (__bf16)fmaxf(acc2[2*kk + (i>>2)][i & 3], 0.0f);

      // ---- layer 3: [64->5] ----
      f32x4 acc3 = (f32x4){b3r[0], b3r[1], b3r[2], b3r[3]};
      acc3 = MFMA(a3[0], z[0], acc3);
      acc3 = MFMA(a3[1], z[1], acc3);

      // ---- store: out feature m = 4q+r, row = 16tt+e ----
      const int rowi = tt * 16 + e;
      if (rowi < n_rows) {
        float* orow = out + (size_t)rowi * 5;
        if (q == 0) {
          orow[0] = acc3[0]; orow[1] = acc3[1];
          orow[2] = acc3[2]; orow[3] = acc3[3];
        } else if (q == 1) {
          orow[4] = acc3[0];
        }
      }
    };

    // ---------------- main loop: 2 tiles per iteration, pair-deep prefetch ----------------
    int p = wid;
    f32x4 c00, c01, c02, c03, c10, c11, c12, c13;
    float s0 = 0.f, s1 = 0.f;
    if (p < n_pairs) {
      issue(2*p,     c00, c01, c02, c03, s0);
      issue(2*p + 1, c10, c11, c12, c13, s1);
    }

    for (; p < n_pairs; p += nw) {
      f32x4 n00, n01, n02, n03, n10, n11, n12, n13;
      float t0 = 0.f, t1 = 0.f;
      const int pn = p + nw;
      if (pn < n_pairs) {
        issue(2*pn,     n00, n01, n02, n03, t0);
        issue(2*pn + 1, n10, n11, n12, n13, t1);
      }

      compute_store(c00, c01, c02, c03, s0, 2*p);
      compute_store(c10, c11, c12, c13, s1, 2*p + 1);

      c00 = n00; c01 = n01; c02 = n02; c03 = n03; s0 = t0;
      c10 = n10; c11 = n11; c12 = n12; c13 = n13; s1 = t1;
    }
}

extern "C" void kernel_launch(void* const* d_in, const int* in_sizes, int n_in,
                              void* d_out, int out_size, void* d_ws, size_t ws_size,
                              hipStream_t stream) {
    const float* h     = (const float*)d_in[0];
    const float* J     = (const float*)d_in[1];
    const float* b_in  = (const float*)d_in[2];
    const float* b_out = (const float*)d_in[3];
    const float* W1    = (const float*)d_in[4];
    const float* b1    = (const float*)d_in[5];
    const float* W2    = (const float*)d_in[6];
    const float* b2    = (const float*)d_in[7];
    const float* W3    = (const float*)d_in[8];
    const float* b3    = (const float*)d_in[9];
    float* out = (float*)d_out;

    const int n_rows  = in_sizes[1];            // J has B*E elements
    const int n_pairs = (n_rows + 31) / 32;     // 32 rows per wave-iteration

    dim3 grid(512), block(256);                 // 2 blocks/CU at <=256 VGPR
    hipLaunchKernelGGL(msg_mlp, grid, block, 0, stream,
                       h, J, b_in, b_out, W1, b1, W2, b2, W3, b3,
                       out, n_rows, n_pairs);
}

// Round 3
// 96.901 us; speedup vs baseline: 1.0636x; 1.0636x over previous
//
#include <hip/hip_runtime.h>

typedef __bf16 bf16x8 __attribute__((ext_vector_type(8)));
typedef float  f32x4  __attribute__((ext_vector_type(4)));

typedef const void GV __attribute__((address_space(1)));
typedef void       LV __attribute__((address_space(3)));

#define MFMA(A, B, C) __builtin_amdgcn_mfma_f32_16x16x32_bf16((A), (B), (C), 0, 0, 0)
#define GLL(gp, lp) __builtin_amdgcn_global_load_lds((GV*)(gp), (LV*)(lp), 16, 0, 0)

// Fused MLP: x=[h(64),b_in,b_out,J,-J] -> 64 relu -> 64 relu -> 5
// Out^T = W^T X^T per 16-row tile, mfma_f32_16x16x32_bf16, rows at lane&15.
// Tile staging: 4x global_load_lds_dwordx4, each 1KB wave-contiguous (16 lines
// vs 64 for fragment-pattern register loads). Chunk involution perm(c)=c^((c>>4)&7)
// applied on the GLOBAL source (global_load_lds dest is linear, rule 21); the
// ds_read side applies the same XOR -> analytically conflict-free b128 reads.
// Wave-private LDS (8KB dbuf/wave), no barriers. Fence: s_waitcnt vmcnt(5)
// (in-order retirement => newest-5 = next tile's 4 staging + 1 scalar load).
__global__ __launch_bounds__(256, 2)
void msg_mlp(const float* __restrict__ hbuf, const float* __restrict__ Jbuf,
             const float* __restrict__ binb, const float* __restrict__ boutb,
             const float* __restrict__ W1, const float* __restrict__ b1,
             const float* __restrict__ W2, const float* __restrict__ b2,
             const float* __restrict__ W3, const float* __restrict__ b3,
             float* __restrict__ out, int n_rows, int n_tiles)
{
    __shared__ __align__(16) char smem[32768];   // 4 waves x 2 bufs x 4KB
    const int lane = threadIdx.x & 63;
    const int e = lane & 15;   // row-within-tile (B n-index and D col)
    const int q = lane >> 4;   // k-group
    const int wv = (int)(threadIdx.x >> 6);
    const int wid = blockIdx.x * 4 + wv;
    const int nw  = gridDim.x * 4;
    char* wbase = smem + wv * 8192;

    // ---- swizzle constants (perm(c) = c ^ ((c>>4)&7), chunk = 16B unit) ----
    const int o_e = 16 * (lane ^ q);          // staging source offset, even j
    const int o_o = 16 * (lane ^ (q + 4));    // staging source offset, odd j
    const int X   = (e & 7) << 4;             // read-side XOR (byte units)
    const int d0 = 256*e + ((64*q +  0) ^ X); // ds_read byte addrs, chunks c'=0..3
    const int d1 = 256*e + ((64*q + 16) ^ X);
    const int d2 = 256*e + ((64*q + 32) ^ X);
    const int d3 = 256*e + ((64*q + 48) ^ X);

    // ---------------- weight fragments (register-resident, loaded once) ----------------
    bf16x8 a1[4][2];   // layer1 h-features, f = 16q + 8kk + i
#pragma unroll
    for (int mt = 0; mt < 4; ++mt)
#pragma unroll
      for (int kk = 0; kk < 2; ++kk)
#pragma unroll
        for (int i = 0; i < 8; ++i)
          a1[mt][kk][i] = (__bf16)W1[(16*q + 8*kk + i)*64 + 16*mt + e];

    bf16x8 a1x[4];     // layer1 scalar features + bias column
#pragma unroll
    for (int mt = 0; mt < 4; ++mt) {
      const int o = 16*mt + e;
      float w0;
      if      (q == 0) w0 =  W1[64*64 + o];   // b_in
      else if (q == 1) w0 =  W1[65*64 + o];   // b_out
      else if (q == 2) w0 =  W1[66*64 + o];   // J
      else             w0 = -W1[67*64 + o];   // -J: sign folded into weight
      a1x[mt][0] = (__bf16)w0;
      a1x[mt][1] = (q == 0) ? (__bf16)b1[o] : (__bf16)0.0f;
#pragma unroll
      for (int i = 2; i < 8; ++i) a1x[mt][i] = (__bf16)0.0f;
    }

    bf16x8 a2[4][2];   // layer2: K=64
#pragma unroll
    for (int mt = 0; mt < 4; ++mt)
#pragma unroll
      for (int kk = 0; kk < 2; ++kk)
#pragma unroll
        for (int i = 0; i < 8; ++i) {
          const int f = 16*(2*kk + (i>>2)) + 4*q + (i&3);
          a2[mt][kk][i] = (__bf16)W2[f*64 + 16*mt + e];
        }
    bf16x8 a3[2];      // layer3: 5 outs (rest zero)
#pragma unroll
    for (int kk = 0; kk < 2; ++kk)
#pragma unroll
      for (int i = 0; i < 8; ++i) {
        const int f = 16*(2*kk + (i>>2)) + 4*q + (i&3);
        a3[kk][i] = (e < 5) ? (__bf16)W3[f*5 + e] : (__bf16)0.0f;
      }
    float b2r[4][4];   // D layout: out = 16mt + 4q + r
#pragma unroll
    for (int mt = 0; mt < 4; ++mt)
#pragma unroll
      for (int r = 0; r < 4; ++r) b2r[mt][r] = b2[16*mt + 4*q + r];
    float b3r[4];
#pragma unroll
    for (int r = 0; r < 4; ++r) b3r[r] = (4*q + r < 5) ? b3[4*q + r] : 0.0f;

    // per-lane uniform scalar stream (no divergence; q==3 reads +J, sign in weight)
    const float* sptr = (q == 0) ? binb : (q == 1) ? boutb : Jbuf;
    const __bf16 biasf = (q == 0) ? (__bf16)1.0f : (__bf16)0.0f;

    // ---- stage one 4KB tile: 4 wave-contiguous 1KB loads, source pre-swizzled ----
    auto stage = [&](int tt, char* dst) {
      const char* g = (const char*)hbuf + (size_t)tt * 4096;
      GLL(g +        o_e, dst);
      GLL(g + 1024 + o_o, dst + 1024);
      GLL(g + 2048 + o_e, dst + 2048);
      GLL(g + 3072 + o_o, dst + 3072);
    };

    int t = wid;
    if (t >= n_tiles) return;            // wave-private LDS, no barriers: safe
    stage(t, wbase);
    float scur = sptr[(size_t)t * 16 + e];
    int cur = 0;

    for (; t < n_tiles; t += nw) {
      int tn = t + nw; if (tn >= n_tiles) tn = t;      // clamped, UNCONDITIONAL
      stage(tn, wbase + ((cur ^ 1) << 12));            // prefetch next tile
      float snext = sptr[(size_t)tn * 16 + e];

      // wait: everything but the newest 5 (= next tile's loads) retired
      asm volatile("s_waitcnt vmcnt(5)" ::: "memory");

      const char* src = wbase + (cur << 12);
      const f32x4 v0 = *(const f32x4*)(src + d0);
      const f32x4 v1 = *(const f32x4*)(src + d1);
      const f32x4 v2 = *(const f32x4*)(src + d2);
      const f32x4 v3 = *(const f32x4*)(src + d3);

      // pack x -> bf16 B-fragments
      bf16x8 xb0, xb1, xb2;
#pragma unroll
      for (int i = 0; i < 4; ++i) {
        xb0[i]     = (__bf16)v0[i];
        xb0[i + 4] = (__bf16)v1[i];
        xb1[i]     = (__bf16)v2[i];
        xb1[i + 4] = (__bf16)v3[i];
      }
      xb2[0] = (__bf16)scur; xb2[1] = biasf;
#pragma unroll
      for (int i = 2; i < 8; ++i) xb2[i] = (__bf16)0.0f;

      // ---- layer 1: [68->64] + relu ----
      f32x4 acc1[4];
#pragma unroll
      for (int mt = 0; mt < 4; ++mt) {
        acc1[mt] = (f32x4){0.f, 0.f, 0.f, 0.f};
        acc1[mt] = MFMA(a1[mt][0], xb0, acc1[mt]);
        acc1[mt] = MFMA(a1[mt][1], xb1, acc1[mt]);
        acc1[mt] = MFMA(a1x[mt],   xb2, acc1[mt]);
      }
      bf16x8 y[2];   // lane-local repack
#pragma unroll
      for (int kk = 0; kk < 2; ++kk)
#pragma unroll
        for (int i = 0; i < 8; ++i)
          y[kk][i] = (__bf16)fmaxf(acc1[2*kk + (i>>2)][i & 3], 0.0f);

      // ---- layer 2: [64->64] + relu ----
      f32x4 acc2[4];
#pragma unroll
      for (int mt = 0; mt < 4; ++mt) {
        acc2[mt] = (f32x4){b2r[mt][0], b2r[mt][1], b2r[mt][2], b2r[mt][3]};
        acc2[mt] = MFMA(a2[mt][0], y[0], acc2[mt]);
        acc2[mt] = MFMA(a2[mt][1], y[1], acc2[mt]);
      }
      bf16x8 z[2];
#pragma unroll
      for (int kk = 0; kk < 2; ++kk)
#pragma unroll
        for (int i = 0; i < 8; ++i)
          z[kk][i] = (__bf16)fmaxf(acc2[2*kk + (i>>2)][i & 3], 0.0f);

      // ---- layer 3: [64->5] ----
      f32x4 acc3 = (f32x4){b3r[0], b3r[1], b3r[2], b3r[3]};
      acc3 = MFMA(a3[0], z[0], acc3);
      acc3 = MFMA(a3[1], z[1], acc3);

      // ---- store: out feature m = 4q+r, row = 16t+e ----
      const int rowi = t * 16 + e;
      if (rowi < n_rows) {
        float* orow = out + (size_t)rowi * 5;
        if (q == 0) {
          orow[0] = acc3[0]; orow[1] = acc3[1];
          orow[2] = acc3[2]; orow[3] = acc3[3];
        } else if (q == 1) {
          orow[4] = acc3[0];
        }
      }
      // keep stores above next iteration's stage in the schedule
      __builtin_amdgcn_sched_barrier(0);

      scur = snext;
      cur ^= 1;
    }
}

extern "C" void kernel_launch(void* const* d_in, const int* in_sizes, int n_in,
                              void* d_out, int out_size, void* d_ws, size_t ws_size,
                              hipStream_t stream) {
    const float* h     = (const float*)d_in[0];
    const float* J     = (const float*)d_in[1];
    const float* b_in  = (const float*)d_in[2];
    const float* b_out = (const float*)d_in[3];
    const float* W1    = (const float*)d_in[4];
    const float* b1    = (const float*)d_in[5];
    const float* W2    = (const float*)d_in[6];
    const float* b2    = (const float*)d_in[7];
    const float* W3    = (const float*)d_in[8];
    const float* b3    = (const float*)d_in[9];
    float* out = (float*)d_out;

    const int n_rows  = in_sizes[1];            // J has B*E elements
    const int n_tiles = (n_rows + 15) / 16;

    dim3 grid(512), block(256);                 // 2 blocks/CU, 32KB LDS each
    hipLaunchKernelGGL(msg_mlp, grid, block, 0, stream,
                       h, J, b_in, b_out, W1, b1, W2, b2, W3, b3,
                       out, n_rows, n_tiles);
}

// Round 4
// 96.835 us; speedup vs baseline: 1.0643x; 1.0007x over previous
//
#include <hip/hip_runtime.h>

typedef __bf16 bf16x8 __attribute__((ext_vector_type(8)));
typedef float  f32x4  __attribute__((ext_vector_type(4)));

typedef const void GV __attribute__((address_space(1)));
typedef void       LV __attribute__((address_space(3)));

#define MFMA(A, B, C) __builtin_amdgcn_mfma_f32_16x16x32_bf16((A), (B), (C), 0, 0, 0)
#define GLL(gp, lp) __builtin_amdgcn_global_load_lds((GV*)(gp), (LV*)(lp), 16, 0, 0)

// Fused MLP: x=[h(64),b_in,b_out,J,-J] -> 64 relu -> 64 relu -> 5
// Out^T = W^T X^T per 16-row tile, mfma_f32_16x16x32_bf16, rows at lane&15.
// R4 change: triple-buffered LDS staging, 2 tile-stages in flight per wave
// (8 KB/wave, 64 KB/CU) -- zero extra VGPRs vs R3's 1-deep pipeline.
// Counted waits: peeled first tile vmcnt(10); steady-state vmcnt(12)
//   newest-12 = stage(t+1)[5] + stores(t-1)[>=2] + stage(t+2)[5]
// so we only ever wait on tile t's stage group + 2-iter-old stores.
__global__ __launch_bounds__(256, 2)
void msg_mlp(const float* __restrict__ hbuf, const float* __restrict__ Jbuf,
             const float* __restrict__ binb, const float* __restrict__ boutb,
             const float* __restrict__ W1, const float* __restrict__ b1,
             const float* __restrict__ W2, const float* __restrict__ b2,
             const float* __restrict__ W3, const float* __restrict__ b3,
             float* __restrict__ out, int n_rows, int n_tiles)
{
    __shared__ __align__(16) char smem[49152];   // 4 waves x 3 bufs x 4KB
    const int lane = threadIdx.x & 63;
    const int e = lane & 15;   // row-within-tile (B n-index and D col)
    const int q = lane >> 4;   // k-group
    const int wv = (int)(threadIdx.x >> 6);
    const int wid = blockIdx.x * 4 + wv;
    const int nw  = gridDim.x * 4;
    char* wbase = smem + wv * 12288;

    // ---- swizzle constants (perm(c) = c ^ ((c>>4)&7), chunk = 16B unit) ----
    const int o_e = 16 * (lane ^ q);          // staging source offset, even j
    const int o_o = 16 * (lane ^ (q + 4));    // staging source offset, odd j
    const int X   = (e & 7) << 4;             // read-side XOR (byte units)
    const int d0 = 256*e + ((64*q +  0) ^ X); // ds_read byte addrs, chunks 0..3
    const int d1 = 256*e + ((64*q + 16) ^ X);
    const int d2 = 256*e + ((64*q + 32) ^ X);
    const int d3 = 256*e + ((64*q + 48) ^ X);

    // ---------------- weight fragments (register-resident, loaded once) ----------------
    bf16x8 a1[4][2];   // layer1 h-features, f = 16q + 8kk + i
#pragma unroll
    for (int mt = 0; mt < 4; ++mt)
#pragma unroll
      for (int kk = 0; kk < 2; ++kk)
#pragma unroll
        for (int i = 0; i < 8; ++i)
          a1[mt][kk][i] = (__bf16)W1[(16*q + 8*kk + i)*64 + 16*mt + e];

    bf16x8 a1x[4];     // layer1 scalar features + bias column
#pragma unroll
    for (int mt = 0; mt < 4; ++mt) {
      const int o = 16*mt + e;
      float w0;
      if      (q == 0) w0 =  W1[64*64 + o];   // b_in
      else if (q == 1) w0 =  W1[65*64 + o];   // b_out
      else if (q == 2) w0 =  W1[66*64 + o];   // J
      else             w0 = -W1[67*64 + o];   // -J: sign folded into weight
      a1x[mt][0] = (__bf16)w0;
      a1x[mt][1] = (q == 0) ? (__bf16)b1[o] : (__bf16)0.0f;
#pragma unroll
      for (int i = 2; i < 8; ++i) a1x[mt][i] = (__bf16)0.0f;
    }

    bf16x8 a2[4][2];   // layer2: K=64
#pragma unroll
    for (int mt = 0; mt < 4; ++mt)
#pragma unroll
      for (int kk = 0; kk < 2; ++kk)
#pragma unroll
        for (int i = 0; i < 8; ++i) {
          const int f = 16*(2*kk + (i>>2)) + 4*q + (i&3);
          a2[mt][kk][i] = (__bf16)W2[f*64 + 16*mt + e];
        }
    bf16x8 a3[2];      // layer3: 5 outs (rest zero)
#pragma unroll
    for (int kk = 0; kk < 2; ++kk)
#pragma unroll
      for (int i = 0; i < 8; ++i) {
        const int f = 16*(2*kk + (i>>2)) + 4*q + (i&3);
        a3[kk][i] = (e < 5) ? (__bf16)W3[f*5 + e] : (__bf16)0.0f;
      }
    float b2r[4][4];   // D layout: out = 16mt + 4q + r
#pragma unroll
    for (int mt = 0; mt < 4; ++mt)
#pragma unroll
      for (int r = 0; r < 4; ++r) b2r[mt][r] = b2[16*mt + 4*q + r];
    float b3r[4];
#pragma unroll
    for (int r = 0; r < 4; ++r) b3r[r] = (4*q + r < 5) ? b3[4*q + r] : 0.0f;

    // per-lane uniform scalar stream (no divergence; q==3 reads +J, sign in weight)
    const float* sptr = (q == 0) ? binb : (q == 1) ? boutb : Jbuf;
    const __bf16 biasf = (q == 0) ? (__bf16)1.0f : (__bf16)0.0f;

    // ---- stage one 4KB tile: 4 wave-contiguous 1KB loads, source pre-swizzled ----
    auto stage = [&](int tt, char* dst) {
      const char* g = (const char*)hbuf + (size_t)tt * 4096;
      GLL(g +        o_e, dst);
      GLL(g + 1024 + o_o, dst + 1024);
      GLL(g + 2048 + o_e, dst + 2048);
      GLL(g + 3072 + o_o, dst + 3072);
    };

    auto compute_store = [&](const char* src, float s, int tt) {
      const f32x4 v0 = *(const f32x4*)(src + d0);
      const f32x4 v1 = *(const f32x4*)(src + d1);
      const f32x4 v2 = *(const f32x4*)(src + d2);
      const f32x4 v3 = *(const f32x4*)(src + d3);

      bf16x8 xb0, xb1, xb2;
#pragma unroll
      for (int i = 0; i < 4; ++i) {
        xb0[i]     = (__bf16)v0[i];
        xb0[i + 4] = (__bf16)v1[i];
        xb1[i]     = (__bf16)v2[i];
        xb1[i + 4] = (__bf16)v3[i];
      }
      xb2[0] = (__bf16)s; xb2[1] = biasf;
#pragma unroll
      for (int i = 2; i < 8; ++i) xb2[i] = (__bf16)0.0f;

      // ---- layer 1: [68->64] + relu ----
      f32x4 acc1[4];
#pragma unroll
      for (int mt = 0; mt < 4; ++mt) {
        acc1[mt] = (f32x4){0.f, 0.f, 0.f, 0.f};
        acc1[mt] = MFMA(a1[mt][0], xb0, acc1[mt]);
        acc1[mt] = MFMA(a1[mt][1], xb1, acc1[mt]);
        acc1[mt] = MFMA(a1x[mt],   xb2, acc1[mt]);
      }
      bf16x8 y[2];   // lane-local repack
#pragma unroll
      for (int kk = 0; kk < 2; ++kk)
#pragma unroll
        for (int i = 0; i < 8; ++i)
          y[kk][i] = (__bf16)fmaxf(acc1[2*kk + (i>>2)][i & 3], 0.0f);

      // ---- layer 2: [64->64] + relu ----
      f32x4 acc2[4];
#pragma unroll
      for (int mt = 0; mt < 4; ++mt) {
        acc2[mt] = (f32x4){b2r[mt][0], b2r[mt][1], b2r[mt][2], b2r[mt][3]};
        acc2[mt] = MFMA(a2[mt][0], y[0], acc2[mt]);
        acc2[mt] = MFMA(a2[mt][1], y[1], acc2[mt]);
      }
      bf16x8 z[2];
#pragma unroll
      for (int kk = 0; kk < 2; ++kk)
#pragma unroll
        for (int i = 0; i < 8; ++i)
          z[kk][i] = (__bf16)fmaxf(acc2[2*kk + (i>>2)][i & 3], 0.0f);

      // ---- layer 3: [64->5] ----
      f32x4 acc3 = (f32x4){b3r[0], b3r[1], b3r[2], b3r[3]};
      acc3 = MFMA(a3[0], z[0], acc3);
      acc3 = MFMA(a3[1], z[1], acc3);

      // ---- store: out feature m = 4q+r, row = 16tt+e ----
      const int rowi = tt * 16 + e;
      if (rowi < n_rows) {
        float* orow = out + (size_t)rowi * 5;
        if (q == 0) {
          orow[0] = acc3[0]; orow[1] = acc3[1];
          orow[2] = acc3[2]; orow[3] = acc3[3];
        } else if (q == 1) {
          orow[4] = acc3[0];
        }
      }
      // pin stores before the next iteration's stage group (vmcnt counting)
      __builtin_amdgcn_sched_barrier(0);
    };

    // ---------------- depth-2 pipeline ----------------
    int t = wid;
    if (t >= n_tiles) return;            // wave-private LDS, no barriers: safe
    const int last = n_tiles - 1;

    char* bufA = wbase;                  // tile t
    char* bufB = wbase + 4096;           // tile t+nw
    char* bufC = wbase + 8192;           // tile t+2nw

    const int tB = (t +   nw <= last) ? t +   nw : last;
    const int tC = (t + 2*nw <= last) ? t + 2*nw : last;
    stage(t,  bufA); float sA = sptr[(size_t)t  * 16 + e];
    stage(tB, bufB); float sB = sptr[(size_t)tB * 16 + e];
    stage(tC, bufC); float sC = sptr[(size_t)tC * 16 + e];

    // peeled first tile: allow the 2 newer stage groups (10 ops) outstanding
    asm volatile("s_waitcnt vmcnt(10)" ::: "memory");
    compute_store(bufA, sA, t);

    for (t += nw; t < n_tiles; t += nw) {
      const int tp = (t + 2*nw <= last) ? t + 2*nw : last;
      stage(tp, bufA);                   // bufA's old tile already consumed
      const float sN = sptr[(size_t)tp * 16 + e];

      // newest-12 = stage(t+1)[5] + stores(t-1)[2] + stage(t+2)[5]
      asm volatile("s_waitcnt vmcnt(12)" ::: "memory");

      compute_store(bufB, sB, t);        // current tile lives in bufB

      char* tmp = bufA; bufA = bufB; bufB = bufC; bufC = tmp;
      sB = sC; sC = sN;
    }
}

extern "C" void kernel_launch(void* const* d_in, const int* in_sizes, int n_in,
                              void* d_out, int out_size, void* d_ws, size_t ws_size,
                              hipStream_t stream) {
    const float* h     = (const float*)d_in[0];
    const float* J     = (const float*)d_in[1];
    const float* b_in  = (const float*)d_in[2];
    const float* b_out = (const float*)d_in[3];
    const float* W1    = (const float*)d_in[4];
    const float* b1    = (const float*)d_in[5];
    const float* W2    = (const float*)d_in[6];
    const float* b2    = (const float*)d_in[7];
    const float* W3    = (const float*)d_in[8];
    const float* b3    = (const float*)d_in[9];
    float* out = (float*)d_out;

    const int n_rows  = in_sizes[1];            // J has B*E elements
    const int n_tiles = (n_rows + 15) / 16;

    dim3 grid(512), block(256);                 // 2 blocks/CU, 48KB LDS each
    hipLaunchKernelGGL(msg_mlp, grid, block, 0, stream,
                       h, J, b_in, b_out, W1, b1, W2, b2, W3, b3,
                       out, n_rows, n_tiles);
}

// Round 5
// 92.521 us; speedup vs baseline: 1.1139x; 1.0466x over previous
//
#include <hip/hip_runtime.h>

typedef __bf16 bf16x8 __attribute__((ext_vector_type(8)));
typedef float  f32x4  __attribute__((ext_vector_type(4)));

#define MFMA(A, B, C) __builtin_amdgcn_mfma_f32_16x16x32_bf16((A), (B), (C), 0, 0, 0)

// Fused MLP: x=[h(64),b_in,b_out,J,-J] -> 64 relu -> 64 relu -> 5
// Out^T = W^T X^T per 16-row tile, rows at lane&15 (e), k-group q=lane>>4.
// R5: weights live in LDS (27 frag-slots x 1KB, fragment layout, re-read per
// tile via conflict-free lane*16 ds_read_b128) instead of ~108 VGPRs ->
// VGPR <= 128 -> 4 blocks/CU = 16 waves/CU (2x concurrency vs R1-R4).
// No software pipeline: pure TLP, LayerNorm-style grid-stride loop.
// Frag slot map (1KB each):
//   a1[mt][kk] -> mt*2+kk   (0..7)    layer1 h-weights, f = 16q+8kk+i
//   a1x[mt]    -> 8+mt      (8..11)   layer1 scalar-feat + bias column
//   a2[mt][kk] -> 12+mt*2+kk(12..19)  layer2, f = 16*(2kk+(i>>2))+4q+(i&3)
//   a3[kk]     -> 20+kk     (20..21)  layer3
//   b2r[mt]    -> 22+mt     (22..25)  f32x4 bias, out = 16mt+4q+r
//   b3r        -> 26                  f32x4 bias
__global__ __launch_bounds__(256, 4)
void msg_mlp(const float* __restrict__ hbuf, const float* __restrict__ Jbuf,
             const float* __restrict__ binb, const float* __restrict__ boutb,
             const float* __restrict__ W1, const float* __restrict__ b1,
             const float* __restrict__ W2, const float* __restrict__ b2,
             const float* __restrict__ W3, const float* __restrict__ b3,
             float* __restrict__ out, int n_rows, int n_tiles)
{
    __shared__ __align__(16) char wlds[27 * 1024];
    const int lane = threadIdx.x & 63;
    const int e = lane & 15;   // row-within-tile (B n-index and D col)
    const int q = lane >> 4;   // k-group
    const int wv = (int)(threadIdx.x >> 6);
    const int wid = blockIdx.x * 4 + wv;
    const int nw  = gridDim.x * 4;
    char* slot = wlds + lane * 16;           // + frag*1024

    // ---------------- weight-fragment init (split across the 4 waves) ----------------
    if (wv == 0) {               // a1 (8 frags) + a1x (4 frags)
#pragma unroll
      for (int mt = 0; mt < 4; ++mt)
#pragma unroll
        for (int kk = 0; kk < 2; ++kk) {
          bf16x8 v;
#pragma unroll
          for (int i = 0; i < 8; ++i)
            v[i] = (__bf16)W1[(16*q + 8*kk + i)*64 + 16*mt + e];
          *(bf16x8*)(slot + (mt*2 + kk) * 1024) = v;
        }
#pragma unroll
      for (int mt = 0; mt < 4; ++mt) {
        const int o = 16*mt + e;
        float w0;
        if      (q == 0) w0 =  W1[64*64 + o];   // b_in
        else if (q == 1) w0 =  W1[65*64 + o];   // b_out
        else if (q == 2) w0 =  W1[66*64 + o];   // J
        else             w0 = -W1[67*64 + o];   // -J: sign folded into weight
        bf16x8 v;
        v[0] = (__bf16)w0;
        v[1] = (q == 0) ? (__bf16)b1[o] : (__bf16)0.0f;
#pragma unroll
        for (int i = 2; i < 8; ++i) v[i] = (__bf16)0.0f;
        *(bf16x8*)(slot + (8 + mt) * 1024) = v;
      }
    } else if (wv == 1) {        // a2 (8 frags)
#pragma unroll
      for (int mt = 0; mt < 4; ++mt)
#pragma unroll
        for (int kk = 0; kk < 2; ++kk) {
          bf16x8 v;
#pragma unroll
          for (int i = 0; i < 8; ++i) {
            const int f = 16*(2*kk + (i>>2)) + 4*q + (i&3);
            v[i] = (__bf16)W2[f*64 + 16*mt + e];
          }
          *(bf16x8*)(slot + (12 + mt*2 + kk) * 1024) = v;
        }
    } else if (wv == 2) {        // a3 (2 frags) + b3r
#pragma unroll
      for (int kk = 0; kk < 2; ++kk) {
        bf16x8 v;
#pragma unroll
        for (int i = 0; i < 8; ++i) {
          const int f = 16*(2*kk + (i>>2)) + 4*q + (i&3);
          v[i] = (e < 5) ? (__bf16)W3[f*5 + e] : (__bf16)0.0f;
        }
        *(bf16x8*)(slot + (20 + kk) * 1024) = v;
      }
      f32x4 v3;
#pragma unroll
      for (int r = 0; r < 4; ++r) v3[r] = (4*q + r < 5) ? b3[4*q + r] : 0.0f;
      *(f32x4*)(slot + 26 * 1024) = v3;
    } else {                     // b2r (4 frags)
#pragma unroll
      for (int mt = 0; mt < 4; ++mt) {
        f32x4 v;
#pragma unroll
        for (int r = 0; r < 4; ++r) v[r] = b2[16*mt + 4*q + r];
        *(f32x4*)(slot + (22 + mt) * 1024) = v;
      }
    }

    // per-lane uniform scalar stream (no divergence; q>=2 reads +J, sign in weight)
    const float* sptr = (q == 0) ? binb : (q == 1) ? boutb : Jbuf;
    const __bf16 biasf = (q == 0) ? (__bf16)1.0f : (__bf16)0.0f;

    __syncthreads();

    // ---------------- main loop: grid-stride, no SW pipeline (TLP covers latency) ----------------
#pragma unroll 1
    for (int t = wid; t < n_tiles; t += nw) {
      int z0 = 0;
      asm volatile("" : "+s"(z0));           // opaque 0: defeat LICM on weight reads
      const char* Wf = slot + z0;

      int re = t * 16 + e;
      if (re >= n_rows) re = n_rows - 1;     // clamp (garbage compute, store guarded)
      const float* hr = hbuf + (size_t)re * 64 + q * 16;
      const f32x4 v0 = *(const f32x4*)(hr);
      const f32x4 v1 = *(const f32x4*)(hr + 4);
      const f32x4 v2 = *(const f32x4*)(hr + 8);
      const f32x4 v3 = *(const f32x4*)(hr + 12);
      const float s  = sptr[re];

      // pack x -> bf16 B-fragments
      bf16x8 xb0, xb1, xb2;
#pragma unroll
      for (int i = 0; i < 4; ++i) {
        xb0[i]     = (__bf16)v0[i];
        xb0[i + 4] = (__bf16)v1[i];
        xb1[i]     = (__bf16)v2[i];
        xb1[i + 4] = (__bf16)v3[i];
      }
      xb2[0] = (__bf16)s; xb2[1] = biasf;
#pragma unroll
      for (int i = 2; i < 8; ++i) xb2[i] = (__bf16)0.0f;

      // ---- layer 1: [68->64] + relu ----
      f32x4 acc1[4];
#pragma unroll
      for (int mt = 0; mt < 4; ++mt) {
        const bf16x8 wa = *(const bf16x8*)(Wf + (mt*2 + 0) * 1024);
        const bf16x8 wb = *(const bf16x8*)(Wf + (mt*2 + 1) * 1024);
        const bf16x8 wx = *(const bf16x8*)(Wf + (8 + mt)  * 1024);
        acc1[mt] = (f32x4){0.f, 0.f, 0.f, 0.f};
        acc1[mt] = MFMA(wa, xb0, acc1[mt]);
        acc1[mt] = MFMA(wb, xb1, acc1[mt]);
        acc1[mt] = MFMA(wx, xb2, acc1[mt]);
      }
      bf16x8 y[2];   // lane-local repack: y[kk][i] = relu(acc1[2kk+(i>>2)][i&3])
#pragma unroll
      for (int kk = 0; kk < 2; ++kk)
#pragma unroll
        for (int i = 0; i < 8; ++i)
          y[kk][i] = (__bf16)fmaxf(acc1[2*kk + (i>>2)][i & 3], 0.0f);

      // ---- layer 2: [64->64] + relu ----
      f32x4 acc2[4];
#pragma unroll
      for (int mt = 0; mt < 4; ++mt) {
        const bf16x8 wa = *(const bf16x8*)(Wf + (12 + mt*2 + 0) * 1024);
        const bf16x8 wb = *(const bf16x8*)(Wf + (12 + mt*2 + 1) * 1024);
        acc2[mt] = *(const f32x4*)(Wf + (22 + mt) * 1024);
        acc2[mt] = MFMA(wa, y[0], acc2[mt]);
        acc2[mt] = MFMA(wb, y[1], acc2[mt]);
      }
      bf16x8 z[2];
#pragma unroll
      for (int kk = 0; kk < 2; ++kk)
#pragma unroll
        for (int i = 0; i < 8; ++i)
          z[kk][i] = (__bf16)fmaxf(acc2[2*kk + (i>>2)][i & 3], 0.0f);

      // ---- layer 3: [64->5] ----
      f32x4 acc3 = *(const f32x4*)(Wf + 26 * 1024);
      acc3 = MFMA(*(const bf16x8*)(Wf + 20 * 1024), z[0], acc3);
      acc3 = MFMA(*(const bf16x8*)(Wf + 21 * 1024), z[1], acc3);

      // ---- store: out feature m = 4q+r, row = 16t+e ----
      const int rowi = t * 16 + e;
      if (rowi < n_rows) {
        float* orow = out + (size_t)rowi * 5;
        if (q == 0) {
          orow[0] = acc3[0]; orow[1] = acc3[1];
          orow[2] = acc3[2]; orow[3] = acc3[3];
        } else if (q == 1) {
          orow[4] = acc3[0];
        }
      }
    }
}

extern "C" void kernel_launch(void* const* d_in, const int* in_sizes, int n_in,
                              void* d_out, int out_size, void* d_ws, size_t ws_size,
                              hipStream_t stream) {
    const float* h     = (const float*)d_in[0];
    const float* J     = (const float*)d_in[1];
    const float* b_in  = (const float*)d_in[2];
    const float* b_out = (const float*)d_in[3];
    const float* W1    = (const float*)d_in[4];
    const float* b1    = (const float*)d_in[5];
    const float* W2    = (const float*)d_in[6];
    const float* b2    = (const float*)d_in[7];
    const float* W3    = (const float*)d_in[8];
    const float* b3    = (const float*)d_in[9];
    float* out = (float*)d_out;

    const int n_rows  = in_sizes[1];            // J has B*E elements
    const int n_tiles = (n_rows + 15) / 16;

    // 1024 blocks x 4 waves = 4096 waves = 16 waves/CU x 256 CUs exactly
    dim3 grid(1024), block(256);
    hipLaunchKernelGGL(msg_mlp, grid, block, 0, stream,
                       h, J, b_in, b_out, W1, b1, W2, b2, W3, b3,
                       out, n_rows, n_tiles);
}